// Round 10
// baseline (234.141 us; speedup 1.0000x reference)
//
#include <hip/hip_runtime.h>
#include <cstddef>

#define NN 1024
#define CL 384
#define CP 128
#define NH 8
#define KS 32
#define HK 256
#define CKR 16            // chunk rows
#define NB (NN/CKR)       // 64 bodies

template<int CTRL>
__device__ __forceinline__ float dpp_mov(float v) {
    return __int_as_float(__builtin_amdgcn_update_dpp(
        0, __float_as_int(v), CTRL, 0xF, 0xF, true));
}

// async global->LDS, 16B per lane; dest must be linear: wave base + lane*16
__device__ __forceinline__ void glds16(const float* g, float* l) {
    __builtin_amdgcn_global_load_lds(
        (const __attribute__((address_space(1))) unsigned int*)g,
        (__attribute__((address_space(3))) unsigned int*)l, 16, 0, 0);
}

// ---------------- Kernel 1: LayerNorm + value projection ----------------
// value[r][m], m = h*32+c  (row-major, m contiguous)
__global__ __launch_bounds__(256) void k_ln_value(
    const float* __restrict__ local_, const float* __restrict__ ln_scale,
    const float* __restrict__ ln_offset, const float* __restrict__ Wv,
    float* __restrict__ value)
{
    __shared__ float ln_s[4][CL];
    const int tid = threadIdx.x;
    const int w = tid >> 6, lane = tid & 63;
    const int r = blockIdx.x * 4 + w;
    const float* lp = local_ + (size_t)r * CL;
    float x[6]; float s1 = 0.f, s2 = 0.f;
#pragma unroll
    for (int k = 0; k < 6; ++k) { x[k] = lp[lane + 64*k]; s1 += x[k]; s2 += x[k]*x[k]; }
#pragma unroll
    for (int m = 1; m < 64; m <<= 1) { s1 += __shfl_xor(s1, m); s2 += __shfl_xor(s2, m); }
    const float mean = s1 * (1.f/CL);
    const float var  = fmaxf(s2 * (1.f/CL) - mean*mean, 0.f);
    const float rstd = rsqrtf(var + 1e-5f);
#pragma unroll
    for (int k = 0; k < 6; ++k) {
        const int c = lane + 64*k;
        ln_s[w][c] = (x[k]-mean)*rstd*ln_scale[c] + ln_offset[c];
    }
    __syncthreads();
    const int m_ = tid;
    float acc0=0.f, acc1=0.f, acc2=0.f, acc3=0.f;
    for (int c0 = 0; c0 < CL; c0 += 8) {
        float wv[8];
#pragma unroll
        for (int cc = 0; cc < 8; ++cc) wv[cc] = Wv[(size_t)(c0+cc)*HK + m_];
        {
            const float4 a = *(const float4*)&ln_s[0][c0];
            const float4 b = *(const float4*)&ln_s[0][c0+4];
            acc0 += a.x*wv[0]+a.y*wv[1]+a.z*wv[2]+a.w*wv[3]+b.x*wv[4]+b.y*wv[5]+b.z*wv[6]+b.w*wv[7];
        }
        {
            const float4 a = *(const float4*)&ln_s[1][c0];
            const float4 b = *(const float4*)&ln_s[1][c0+4];
            acc1 += a.x*wv[0]+a.y*wv[1]+a.z*wv[2]+a.w*wv[3]+b.x*wv[4]+b.y*wv[5]+b.z*wv[6]+b.w*wv[7];
        }
        {
            const float4 a = *(const float4*)&ln_s[2][c0];
            const float4 b = *(const float4*)&ln_s[2][c0+4];
            acc2 += a.x*wv[0]+a.y*wv[1]+a.z*wv[2]+a.w*wv[3]+b.x*wv[4]+b.y*wv[5]+b.z*wv[6]+b.w*wv[7];
        }
        {
            const float4 a = *(const float4*)&ln_s[3][c0];
            const float4 b = *(const float4*)&ln_s[3][c0+4];
            acc3 += a.x*wv[0]+a.y*wv[1]+a.z*wv[2]+a.w*wv[3]+b.x*wv[4]+b.y*wv[5]+b.z*wv[6]+b.w*wv[7];
        }
    }
    const int rb = blockIdx.x*4;
    value[(size_t)(rb+0)*HK + m_] = acc0;
    value[(size_t)(rb+1)*HK + m_] = acc1;
    value[(size_t)(rb+2)*HK + m_] = acc2;
    value[(size_t)(rb+3)*HK + m_] = acc3;
}

// ---------------- Kernel 2: fused attention, all-LDS compute phases ---------
// Body t: glds val(t) ; glds pair(t+1) (dbuf) ; LOGITS(t) [LDS only] ;
//         vmcnt(2)+bar (val visible, pair stays in flight) ; PV(t) [LDS only];
//         vmcnt(0)+bar (pair visible, valB/ps reusable).
__global__ __launch_bounds__(256, 2) void k_attn(
    const float* __restrict__ pair, const int* __restrict__ mask,
    const float* __restrict__ Wa, const float* __restrict__ value,
    const float* __restrict__ Wo, float* __restrict__ outp)
{
    __shared__ float pairB[2][CKR][CP];   // 16 KB, double-buffered
    __shared__ float valB[CKR][HK];       // 16 KB
    __shared__ float zf[NN];              // 4 KB
    __shared__ float ps[NH][CKR+4];       // p~ per (head,row)
    __shared__ float sep[8][NH];          // per-group denominators
    __shared__ float ov4[4][64][4];       // PV partials per wave
    __shared__ float ov[HK];

    const int tid  = threadIdx.x;
    const int g    = tid >> 5;            // 32-lane group 0..7
    const int sub5 = tid & 31;
    const int i = blockIdx.x;
    const bool bmi = mask[i] != 0;

    const float* prow = pair + (size_t)i*NN*CP;

    // stage pair chunk 0 (oldest; drained by the prologue __syncthreads)
    {
        const int r0 = tid >> 5, c0 = (tid & 31) * 4;
        const float* pg = prow + (size_t)r0*CP + c0;
        float* lb = &pairB[0][0][0] + tid*4;
        glds16(pg, lb);
        glds16(pg + (size_t)8*CP, lb + 1024);
    }

    for (int k = tid; k < NN; k += 256)
        zf[k] = (bmi && (mask[k] != 0)) ? 1.f : 0.f;

    // W_attn rows sub5*4 .. +3, all 8 heads; wreg[cc*8+h]
    float wreg[32];
    {
        const float4* wp = (const float4*)(Wa + sub5*4*NH);
#pragma unroll
        for (int k = 0; k < 8; ++k) {
            const float4 t4 = wp[k];
            wreg[4*k+0]=t4.x; wreg[4*k+1]=t4.y; wreg[4*k+2]=t4.z; wreg[4*k+3]=t4.w;
        }
    }

    const int  myh   = (sub5 & 1)*4 + ((sub5 >> 1) & 1)*2 + ((sub5 >> 3) & 1);
    const bool owner = (sub5 & 0x14) == 0;       // one lane per (g, myh)

    const int q  = tid >> 6;                     // PV: wave q -> rows j%4==q
    const int mq = tid & 63;                     // PV: m-quad
    const int pvh = mq >> 3;

    float4 ac4; ac4.x = ac4.y = ac4.z = ac4.w = 0.f;
    float se_loc = 0.f;

    __syncthreads();     // zf ready + pair chunk 0 staged (full drain, once)

    for (int t = 0; t < NB; ++t) {
        const int j0 = t*CKR;
        // ---- S_val(t): 4 glds (oldest this body) ----
        {
            const int r = tid >> 6, c = (tid & 63)*4;
            const float* vg = value + (size_t)(j0 + r)*HK + c;
            float* lb = &valB[0][0] + tid*4;
#pragma unroll
            for (int k = 0; k < 4; ++k)
                glds16(vg + (size_t)(k*4)*HK, lb + k*1024);
        }
        // ---- S_pair(t+1): 2 glds into the other buffer (youngest) ----
        const bool more = (t+1 < NB);
        if (more) {
            const int r0 = tid >> 5, c0 = (tid & 31)*4;
            const float* pg = prow + (size_t)((t+1)*CKR + r0)*CP + c0;
            float* lb = &pairB[(t+1)&1][0][0] + tid*4;
            glds16(pg, lb);
            glds16(pg + (size_t)8*CP, lb + 1024);
        }
        // ---- LOGITS(t): pure LDS + VALU (covers val latency) ----
        {
            const float* pbuf = &pairB[t&1][0][0];
#pragma unroll
            for (int s = 0; s < 2; ++s) {
                const int row = g*2 + s;
                const float4 c = *(const float4*)(pbuf + row*CP + sub5*4);
                float acc[8];
#pragma unroll
                for (int h = 0; h < 8; ++h)
                    acc[h] = c.x*wreg[h] + c.y*wreg[8+h] + c.z*wreg[16+h] + c.w*wreg[24+h];
                const bool b0 = (sub5 & 1) != 0;
                const bool b1 = (sub5 & 2) != 0;
                const bool b3 = (sub5 & 8) != 0;
                float r4[4];
#pragma unroll
                for (int k = 0; k < 4; ++k)
                    r4[k] = (b0 ? acc[k+4] : acc[k]) + dpp_mov<0xB1>(b0 ? acc[k] : acc[k+4]); // xor1
                float r2[2];
#pragma unroll
                for (int k = 0; k < 2; ++k)
                    r2[k] = (b1 ? r4[k+2] : r4[k]) + dpp_mov<0x4E>(b1 ? r4[k] : r4[k+2]);     // xor2
                float r1 = (b3 ? r2[1] : r2[0]) + dpp_mov<0x128>(b3 ? r2[0] : r2[1]);         // xor8
                r1 += __shfl_xor(r1, 4);
                r1 += __shfl_xor(r1, 16);
                const float pt = zf[j0 + row] * __expf(r1);
                se_loc += pt;                 // 4 dup lanes per (g,myh)
                ps[myh][row] = pt;            // dup same-addr same-value writes
            }
        }
        // ---- mid wait: retire val(t); pair(t+1) stays in flight ----
        if (more) asm volatile("s_waitcnt vmcnt(2) lgkmcnt(0)" ::: "memory");
        else      asm volatile("s_waitcnt vmcnt(0) lgkmcnt(0)" ::: "memory");
        __builtin_amdgcn_s_barrier();
        // ---- PV(t): pure LDS ----
        {
#pragma unroll
            for (int k = 0; k < 4; ++k) {
                const int j = k*4 + q;
                const float p = ps[pvh][j];
                const float4 v4 = *(const float4*)(&valB[j][mq*4]);
                ac4.x += p*v4.x; ac4.y += p*v4.y; ac4.z += p*v4.z; ac4.w += p*v4.w;
            }
        }
        // ---- end: pair(t+1) visible; valB/ps safe to overwrite ----
        asm volatile("s_waitcnt vmcnt(0) lgkmcnt(0)" ::: "memory");
        __builtin_amdgcn_s_barrier();
    }

    // ---- epilogue ----
    if (owner) sep[g][myh] = se_loc;
    ov4[q][mq][0] = ac4.x; ov4[q][mq][1] = ac4.y;
    ov4[q][mq][2] = ac4.z; ov4[q][mq][3] = ac4.w;
    __syncthreads();

    {   // combine, normalize
        const int m = tid;               // 0..255
        const float s4 = ov4[0][m>>2][m&3] + ov4[1][m>>2][m&3]
                       + ov4[2][m>>2][m&3] + ov4[3][m>>2][m&3];
        const int h = m >> 5;
        float se = 0.f;
#pragma unroll
        for (int k = 0; k < 8; ++k) se += sep[k][h];
        const float inv = (se > 0.f) ? (1.f/se) : 0.f;
        ov[m] = s4 * inv;
    }
    __syncthreads();

    // ---- final projection out = ov @ W_out ----
    for (int o = tid; o < CL; o += 256) {
        float a0 = 0.f;
        for (int m = 0; m < HK; m += 4) {
            const float4 x0 = *(const float4*)&ov[m];
            a0 += x0.x*Wo[(size_t)(m+0)*CL + o] + x0.y*Wo[(size_t)(m+1)*CL + o]
                + x0.z*Wo[(size_t)(m+2)*CL + o] + x0.w*Wo[(size_t)(m+3)*CL + o];
        }
        outp[(size_t)i*CL + o] = a0;
    }
}

extern "C" void kernel_launch(void* const* d_in, const int* in_sizes, int n_in,
                              void* d_out, int out_size, void* d_ws, size_t ws_size,
                              hipStream_t stream)
{
    (void)in_sizes; (void)n_in; (void)out_size; (void)ws_size;
    const float* local_ = (const float*)d_in[0];
    const float* pair   = (const float*)d_in[1];
    const int*   mask   = (const int*)d_in[2];
    const float* scale  = (const float*)d_in[3];
    const float* offset = (const float*)d_in[4];
    const float* Wv     = (const float*)d_in[5];
    const float* Wa     = (const float*)d_in[6];
    const float* Wo     = (const float*)d_in[7];
    float* value = (float*)d_ws;          // 1 MiB scratch: [1024][256]
    k_ln_value<<<NN/4, 256, 0, stream>>>(local_, scale, offset, Wv, value);
    k_attn<<<NN, 256, 0, stream>>>(pair, mask, Wa, value, Wo, (float*)d_out);
}